// Round 3
// baseline (829.650 us; speedup 1.0000x reference)
//
#include <hip/hip_runtime.h>

#define N_ 768
#define S_ 384
#define H_ 16
#define D_ 48
#define P_ 128
#define NN_ (768*768)

typedef __attribute__((ext_vector_type(8))) short bf16x8;
typedef __attribute__((ext_vector_type(4))) float f32x4;

__device__ __forceinline__ unsigned short f2bf(float x) {
  unsigned int u = __float_as_uint(x);
  u = (u + 0x7fffu + ((u >> 16) & 1u)) >> 16;
  return (unsigned short)u;
}
__device__ __forceinline__ float bf2f(unsigned short h) {
  return __uint_as_float(((unsigned int)h) << 16);
}
__device__ __forceinline__ float sigm(float x) { return 1.f / (1.f + __expf(-x)); }

// ---------------- LN prep: a_n (fp32), s_n (split), s (split), bq4, W', c1/c2 ----------------
__global__ __launch_bounds__(256) void k_ln_prep(
    const float* __restrict__ a, const float* __restrict__ s,
    const float* __restrict__ ln_s_w, const float* __restrict__ bq,
    const float* __restrict__ ln_p_w, const float* __restrict__ ln_p_b,
    const float* __restrict__ Wb,
    float* __restrict__ a_n,
    unsigned short* __restrict__ s_n_hi, unsigned short* __restrict__ s_n_lo,
    unsigned short* __restrict__ s_hi, unsigned short* __restrict__ s_lo,
    float* __restrict__ bq4, float* __restrict__ Wprime, float* __restrict__ c12)
{
  int b = blockIdx.x;
  int t = threadIdx.x;
  if (b == N_) {  // aux block
    for (int j = t; j < 3072; j += 256) bq4[j] = (j < 768) ? bq[j] : 0.f;
    for (int idx = t; idx < 2048; idx += 256) Wprime[idx] = ln_p_w[idx >> 4] * Wb[idx];
    if (t < 16) {
      float c1 = 0.f, c2 = 0.f;
      for (int p = 0; p < 128; ++p) { float wb = Wb[p*16 + t]; c1 += ln_p_w[p]*wb; c2 += ln_p_b[p]*wb; }
      c12[t] = c1; c12[16+t] = c2;
    }
    return;
  }
  __shared__ float red[16];
  int w = t >> 6, l = t & 63;
  // ---- a row (768) ----
  float v0 = a[b*N_ + t], v1 = a[b*N_ + 256 + t], v2 = a[b*N_ + 512 + t];
  float sm = v0+v1+v2, sq = v0*v0 + v1*v1 + v2*v2;
  #pragma unroll
  for (int o = 32; o; o >>= 1) { sm += __shfl_xor(sm, o); sq += __shfl_xor(sq, o); }
  if (l == 0) { red[w] = sm; red[8+w] = sq; }
  __syncthreads();
  float Sa = red[0]+red[1]+red[2]+red[3];
  float Qa = red[8]+red[9]+red[10]+red[11];
  float mean = Sa * (1.f/768.f);
  float var  = Qa * (1.f/768.f) - mean*mean;
  float inv  = rsqrtf(var + 1e-5f);
  a_n[b*N_ + t]       = (v0-mean)*inv;
  a_n[b*N_ + 256 + t] = (v1-mean)*inv;
  a_n[b*N_ + 512 + t] = (v2-mean)*inv;
  __syncthreads();
  // ---- s row (384) ----
  float u0 = s[b*S_ + t];
  float u1 = (t < 128) ? s[b*S_ + 256 + t] : 0.f;
  float sm2 = u0+u1, sq2 = u0*u0 + u1*u1;
  #pragma unroll
  for (int o = 32; o; o >>= 1) { sm2 += __shfl_xor(sm2, o); sq2 += __shfl_xor(sq2, o); }
  if (l == 0) { red[w] = sm2; red[8+w] = sq2; }
  __syncthreads();
  float Ss = red[0]+red[1]+red[2]+red[3];
  float Qs = red[8]+red[9]+red[10]+red[11];
  float means = Ss * (1.f/384.f);
  float vars  = Qs * (1.f/384.f) - means*means;
  float invs  = rsqrtf(vars + 1e-5f);
  {
    float sn = (u0 - means)*invs*ln_s_w[t];
    unsigned short h = f2bf(sn); s_n_hi[b*S_+t] = h; s_n_lo[b*S_+t] = f2bf(sn - bf2f(h));
    unsigned short hr = f2bf(u0); s_hi[b*S_+t] = hr; s_lo[b*S_+t] = f2bf(u0 - bf2f(hr));
  }
  if (t < 128) {
    int c = 256 + t;
    float sn = (u1 - means)*invs*ln_s_w[c];
    unsigned short h = f2bf(sn); s_n_hi[b*S_+c] = h; s_n_lo[b*S_+c] = f2bf(sn - bf2f(h));
    unsigned short hr = f2bf(u1); s_hi[b*S_+c] = hr; s_lo[b*S_+c] = f2bf(u1 - bf2f(hr));
  }
}

// ---------------- transpose + split-convert weights ----------------
struct TDesc { const float* src; unsigned short* hi; unsigned short* lo; int R; int C; };
struct TArgs { TDesc d[8]; };
__global__ __launch_bounds__(256) void k_transpose(TArgs args)
{
  TDesc dd = args.d[blockIdx.z];
  int c0 = blockIdx.x * 32, r0 = blockIdx.y * 32;
  if (r0 >= dd.R || c0 >= dd.C) return;
  __shared__ float tile[32][33];
  int tx = threadIdx.x & 31, ty = threadIdx.x >> 5;
  #pragma unroll
  for (int p = 0; p < 4; ++p) {
    int r = ty + p*8;
    tile[r][tx] = dd.src[(r0 + r)*dd.C + c0 + tx];
  }
  __syncthreads();
  #pragma unroll
  for (int p = 0; p < 4; ++p) {
    int r = ty + p*8;
    float x = tile[tx][r];
    unsigned short h = f2bf(x);
    int oidx = (c0 + r)*dd.R + r0 + tx;
    dd.hi[oidx] = h; dd.lo[oidx] = f2bf(x - bf2f(h));
  }
}

// ---------------- pair bias: bias3[h][i][j] = LN(pair[i,j,:])@Wb + beta[i,j] ----------------
// wave per position; raw-x dot with W' = ln_p_w .* Wb;  bias = inv*(x.W') - inv*mu*c1 + c2 + beta
__global__ __launch_bounds__(256) void k_pair_bias(
    const float* __restrict__ pair, const float* __restrict__ beta,
    const float* __restrict__ Wprime, const float* __restrict__ c12,
    float* __restrict__ bias3)
{
  __shared__ float xbuf[4][128];
  int b = blockIdx.x;
  int i = b >> 1, j0 = (b & 1) * 384;
  int t = threadIdx.x, w = t >> 6, l = t & 63;
  int h = l & 15, pg = l >> 4;
  float wreg[32];
  #pragma unroll
  for (int e = 0; e < 32; ++e) wreg[e] = Wprime[(pg*32 + e)*16 + h];
  float c1 = c12[h], c2 = c12[16 + h];
  for (int j = j0 + w; j < j0 + 384; j += 4) {
    const float* px = pair + ((long)i*N_ + j)*P_;
    float2 x2 = *(const float2*)(px + 2*l);
    *(float2*)&xbuf[w][2*l] = x2;
    float sm = x2.x + x2.y, sq = x2.x*x2.x + x2.y*x2.y;
    #pragma unroll
    for (int o = 32; o; o >>= 1) { sm += __shfl_xor(sm, o); sq += __shfl_xor(sq, o); }
    float mean = sm * (1.f/128.f);
    float var  = sq * (1.f/128.f) - mean*mean;
    float inv  = rsqrtf(var + 1e-5f);
    float acc = 0.f;
    #pragma unroll
    for (int e4 = 0; e4 < 8; ++e4) {
      float4 xv = *(const float4*)&xbuf[w][pg*32 + e4*4];
      acc = fmaf(xv.x, wreg[e4*4+0], acc);
      acc = fmaf(xv.y, wreg[e4*4+1], acc);
      acc = fmaf(xv.z, wreg[e4*4+2], acc);
      acc = fmaf(xv.w, wreg[e4*4+3], acc);
    }
    acc += __shfl_xor(acc, 16);
    acc += __shfl_xor(acc, 32);
    float outv = inv*acc - inv*mean*c1 + c2 + beta[(long)i*N_ + j];
    if (pg == 0) bias3[(long)h*NN_ + (long)i*N_ + j] = outv;
  }
}

// ---------------- generic NT MFMA GEMM (bf16, optional Ootomo split), fused epilogues ----------------
struct GemmArgs {
  const unsigned short* Ah; const unsigned short* Al;
  const unsigned short* Bh; const unsigned short* Bl;
  int lda, ldb, K;
  long sAz, sBz;
  float* C; int ldc; long sCz;
  const float* aux0; const float* aux1;
  unsigned short* oHi; unsigned short* oLo;
  float scale;
};

// EPI: 0=store f32, 1=+biasvec, 2=scores(*scale + bias3[z]), 3=PV(*gate, split-store o), 4=final out
template<int WTM, int WTN, bool SPLIT, int EPI>
__global__ __launch_bounds__(256) void k_gemm(GemmArgs g)
{
  constexpr int BM = 2*WTM*16, BN = 2*WTN*16;
  int z = blockIdx.z;
  int m0 = blockIdx.x * BM, n0 = blockIdx.y * BN;
  int t = threadIdx.x, l = t & 63, w = t >> 6;
  int wm = (w >> 1)*(WTM*16), wn = (w & 1)*(WTN*16);
  int r = l & 15, kg = (l >> 4)*8;
  const unsigned short* Ah = g.Ah + (long)z*g.sAz;
  const unsigned short* Bh = g.Bh + (long)z*g.sBz;
  const unsigned short* Al = nullptr; const unsigned short* Bl = nullptr;
  if constexpr (SPLIT) { Al = g.Al + (long)z*g.sAz; Bl = g.Bl + (long)z*g.sBz; }
  f32x4 acc[WTM][WTN] = {};
  for (int k0 = 0; k0 < g.K; k0 += 32) {
    bf16x8 ah[WTM], bh[WTN], al[WTM], bl[WTN];
    #pragma unroll
    for (int mt = 0; mt < WTM; ++mt) {
      long off = (long)(m0 + wm + mt*16 + r)*g.lda + k0 + kg;
      ah[mt] = *(const bf16x8*)(Ah + off);
      if constexpr (SPLIT) al[mt] = *(const bf16x8*)(Al + off);
    }
    #pragma unroll
    for (int nt = 0; nt < WTN; ++nt) {
      long off = (long)(n0 + wn + nt*16 + r)*g.ldb + k0 + kg;
      bh[nt] = *(const bf16x8*)(Bh + off);
      if constexpr (SPLIT) bl[nt] = *(const bf16x8*)(Bl + off);
    }
    #pragma unroll
    for (int mt = 0; mt < WTM; ++mt) {
      #pragma unroll
      for (int nt = 0; nt < WTN; ++nt) {
        acc[mt][nt] = __builtin_amdgcn_mfma_f32_16x16x32_bf16(ah[mt], bh[nt], acc[mt][nt], 0, 0, 0);
        if constexpr (SPLIT) {
          acc[mt][nt] = __builtin_amdgcn_mfma_f32_16x16x32_bf16(al[mt], bh[nt], acc[mt][nt], 0, 0, 0);
          acc[mt][nt] = __builtin_amdgcn_mfma_f32_16x16x32_bf16(ah[mt], bl[nt], acc[mt][nt], 0, 0, 0);
        }
      }
    }
  }
  int rb = (l >> 4)*4, cl = l & 15;
  #pragma unroll
  for (int mt = 0; mt < WTM; ++mt)
  #pragma unroll
  for (int nt = 0; nt < WTN; ++nt)
  #pragma unroll
  for (int ri = 0; ri < 4; ++ri) {
    int row = m0 + wm + mt*16 + rb + ri;
    int col = n0 + wn + nt*16 + cl;
    float v = acc[mt][nt][ri];
    if constexpr (EPI == 0) {
      g.C[(long)z*g.sCz + (long)row*g.ldc + col] = v;
    } else if constexpr (EPI == 1) {
      g.C[(long)row*g.ldc + col] = v + g.aux0[col];
    } else if constexpr (EPI == 2) {
      g.C[(long)z*g.sCz + (long)row*g.ldc + col] =
          v*g.scale + g.aux0[(long)z*NN_ + (long)row*N_ + col];
    } else if constexpr (EPI == 3) {
      if (col < D_) {
        long oidx = (long)row*N_ + z*D_ + col;
        float val = v * g.aux0[oidx];
        unsigned short hh = f2bf(val);
        g.oHi[oidx] = hh; g.oLo[oidx] = f2bf(val - bf2f(hh));
      }
    } else if constexpr (EPI == 4) {
      float sgv = sigm(v + g.aux1[col]);
      long oidx = (long)row*g.ldc + col;
      g.C[oidx] = sgv * g.aux0[oidx];
    }
  }
}

// ---------------- a2 = sigmoid(gs_gamma + gamma_b) * a_n + gs_shift  (split-store) ----------------
__global__ __launch_bounds__(256) void k_a2(
    const float* __restrict__ gs, const float* __restrict__ gamma_b,
    const float* __restrict__ a_n,
    unsigned short* __restrict__ a2h, unsigned short* __restrict__ a2l)
{
  int i = blockIdx.x;
  int j = blockIdx.y*256 + threadIdx.x;
  float val = sigm(gs[(long)i*1536 + j] + gamma_b[j]) * a_n[(long)i*N_ + j]
            + gs[(long)i*1536 + 768 + j];
  unsigned short h = f2bf(val);
  long idx = (long)i*N_ + j;
  a2h[idx] = h; a2l[idx] = f2bf(val - bf2f(h));
}

// ---------------- qkvg post: qp/kp (bf16, d padded to 64 with zeros), v^T (bf16), gate (fp32) ----------------
__global__ __launch_bounds__(256) void k_qkvg_post(
    const float* __restrict__ qkvg,
    unsigned short* __restrict__ qp, unsigned short* __restrict__ kp,
    unsigned short* __restrict__ vt, float* __restrict__ gg)
{
  int b = blockIdx.x;
  int t = threadIdx.x;
  if (b < N_) {
    long i = b;
    #pragma unroll
    for (int e = 0; e < 4; ++e) {
      int c = t + e*256;            // 0..1023
      int h = c >> 6, d = c & 63;
      float qv = (d < D_) ? qkvg[i*3072 + h*D_ + d] : 0.f;
      float kv = (d < D_) ? qkvg[i*3072 + 768 + h*D_ + d] : 0.f;
      qp[i*1024 + c] = f2bf(qv);
      kp[i*1024 + c] = f2bf(kv);
    }
    #pragma unroll
    for (int e = 0; e < 3; ++e) {
      int c = t + e*256;
      gg[i*N_ + c] = sigm(qkvg[i*3072 + 2304 + c]);
    }
  } else {
    __shared__ float tile[64][49];
    int b2 = b - N_;                // 0..191
    int h = b2 / 12, i0 = (b2 % 12) * 64;
    #pragma unroll
    for (int e = 0; e < 12; ++e) {
      int idx = t + e*256;          // 0..3071
      int il = idx / 48, d = idx % 48;
      tile[il][d] = qkvg[(long)(i0+il)*3072 + 1536 + h*D_ + d];
    }
    __syncthreads();
    #pragma unroll
    for (int e = 0; e < 12; ++e) {
      int idx = t + e*256;
      int d = idx >> 6, il = idx & 63;
      vt[(long)h*49152 + (long)d*N_ + i0 + il] = f2bf(tile[il][d]);
    }
  }
}

// ---------------- softmax over rows of scores -> attn (bf16) ----------------
__global__ __launch_bounds__(256) void k_softmax(
    const float* __restrict__ scores, unsigned short* __restrict__ attn)
{
  int row = blockIdx.x*4 + (threadIdx.x >> 6);
  int l = threadIdx.x & 63;
  const float* src = scores + (long)row*N_;
  float x[12];
  #pragma unroll
  for (int e = 0; e < 12; ++e) x[e] = src[l + e*64];
  float m = x[0];
  #pragma unroll
  for (int e = 1; e < 12; ++e) m = fmaxf(m, x[e]);
  #pragma unroll
  for (int o = 32; o; o >>= 1) m = fmaxf(m, __shfl_xor(m, o));
  float ssum = 0.f;
  #pragma unroll
  for (int e = 0; e < 12; ++e) { x[e] = __expf(x[e] - m); ssum += x[e]; }
  #pragma unroll
  for (int o = 32; o; o >>= 1) ssum += __shfl_xor(ssum, o);
  float invs = 1.f / ssum;
  unsigned short* dst = attn + (long)row*N_;
  #pragma unroll
  for (int e = 0; e < 12; ++e) dst[l + e*64] = f2bf(x[e]*invs);
}

// ---------------- launch ----------------
extern "C" void kernel_launch(void* const* d_in, const int* in_sizes, int n_in,
                              void* d_out, int out_size, void* d_ws, size_t ws_size,
                              hipStream_t stream) {
  const float* a      = (const float*)d_in[0];
  const float* s      = (const float*)d_in[1];
  const float* pair   = (const float*)d_in[2];
  const float* beta   = (const float*)d_in[3];
  const float* ln_s_w = (const float*)d_in[4];
  const float* gamma_w= (const float*)d_in[5];
  const float* gamma_b= (const float*)d_in[6];
  const float* shift_w= (const float*)d_in[7];
  const float* Wq     = (const float*)d_in[8];
  const float* bq     = (const float*)d_in[9];
  const float* Wk     = (const float*)d_in[10];
  const float* Wv     = (const float*)d_in[11];
  const float* ln_p_w = (const float*)d_in[12];
  const float* ln_p_b = (const float*)d_in[13];
  const float* Wb     = (const float*)d_in[14];
  const float* Wg     = (const float*)d_in[15];
  const float* Wp     = (const float*)d_in[16];
  const float* Wout   = (const float*)d_in[17];
  const float* bout   = (const float*)d_in[18];
  float* out = (float*)d_out;
  (void)in_sizes; (void)n_in; (void)out_size; (void)ws_size;

  char* ws = (char*)d_ws;
  size_t off = 0;
  auto alloc = [&](size_t bytes) -> char* {
    char* p = ws + off;
    off = (off + bytes + 255) & ~(size_t)255;
    return p;
  };
  float* bias3   = (float*)alloc((size_t)H_*NN_*4);      // 37.75 MB
  float* scores  = (float*)alloc((size_t)H_*NN_*4);      // 37.75 MB
  unsigned short* W4T_hi  = (unsigned short*)alloc((size_t)3072*768*2);
  unsigned short* W4T_lo  = (unsigned short*)alloc((size_t)3072*768*2);
  unsigned short* gsT_hi  = (unsigned short*)alloc((size_t)1536*384*2);
  unsigned short* gsT_lo  = (unsigned short*)alloc((size_t)1536*384*2);
  unsigned short* WpT_hi  = (unsigned short*)alloc((size_t)768*768*2);
  unsigned short* WpT_lo  = (unsigned short*)alloc((size_t)768*768*2);
  unsigned short* WoT_hi  = (unsigned short*)alloc((size_t)768*384*2);
  unsigned short* WoT_lo  = (unsigned short*)alloc((size_t)768*384*2);
  float* a_n     = (float*)alloc((size_t)N_*N_*4);
  unsigned short* s_n_hi = (unsigned short*)alloc((size_t)N_*S_*2);
  unsigned short* s_n_lo = (unsigned short*)alloc((size_t)N_*S_*2);
  unsigned short* s_hi   = (unsigned short*)alloc((size_t)N_*S_*2);
  unsigned short* s_lo   = (unsigned short*)alloc((size_t)N_*S_*2);
  float* bq4     = (float*)alloc(3072*4);
  float* Wprime  = (float*)alloc(128*16*4);
  float* c12     = (float*)alloc(32*4);
  unsigned short* a2_hi  = (unsigned short*)alloc((size_t)N_*N_*2);
  unsigned short* a2_lo  = (unsigned short*)alloc((size_t)N_*N_*2);
  float* qkvg    = (float*)alloc((size_t)N_*3072*4);     // gs aliases this
  unsigned short* qp = (unsigned short*)alloc((size_t)N_*1024*2);
  unsigned short* kp = (unsigned short*)alloc((size_t)N_*1024*2);
  unsigned short* vt = (unsigned short*)alloc((size_t)H_*64*N_*2);
  float* gate    = (float*)alloc((size_t)N_*N_*4);
  // aliases (dead-buffer reuse)
  float* gs = qkvg;                                   // 768x1536 fp32, dead before GEMM2 writes qkvg
  unsigned short* attn = (unsigned short*)bias3;      // bias3 dead after scores GEMM
  unsigned short* o_hi = (unsigned short*)scores;     // scores dead after softmax
  unsigned short* o_lo = (unsigned short*)((char*)scores + (size_t)N_*N_*2);
  float* out1 = (float*)((char*)scores + (size_t)N_*N_*4);

  dim3 blk(256);

  k_ln_prep<<<dim3(N_ + 1), blk, 0, stream>>>(a, s, ln_s_w, bq, ln_p_w, ln_p_b, Wb,
      a_n, s_n_hi, s_n_lo, s_hi, s_lo, bq4, Wprime, c12);

  TArgs ta;
  ta.d[0] = {gamma_w, gsT_hi,               gsT_lo,               384, 768};
  ta.d[1] = {shift_w, gsT_hi + 768*384,     gsT_lo + 768*384,     384, 768};
  ta.d[2] = {Wq,      W4T_hi,               W4T_lo,               768, 768};
  ta.d[3] = {Wk,      W4T_hi + 1*768*768,   W4T_lo + 1*768*768,   768, 768};
  ta.d[4] = {Wv,      W4T_hi + 2*768*768,   W4T_lo + 2*768*768,   768, 768};
  ta.d[5] = {Wg,      W4T_hi + 3*768*768,   W4T_lo + 3*768*768,   768, 768};
  ta.d[6] = {Wp,      WpT_hi,               WpT_lo,               768, 768};
  ta.d[7] = {Wout,    WoT_hi,               WoT_lo,               384, 768};
  k_transpose<<<dim3(24, 24, 8), blk, 0, stream>>>(ta);

  k_pair_bias<<<dim3(1536), blk, 0, stream>>>(pair, beta, Wprime, c12, bias3);

  GemmArgs g1{};  // gs = s_n @ [gammaT|shiftT]
  g1.Ah = s_n_hi; g1.Al = s_n_lo; g1.Bh = gsT_hi; g1.Bl = gsT_lo;
  g1.lda = 384; g1.ldb = 384; g1.K = 384; g1.C = gs; g1.ldc = 1536;
  k_gemm<4,4,true,0><<<dim3(6,12,1), blk, 0, stream>>>(g1);

  k_a2<<<dim3(768,3), blk, 0, stream>>>(gs, gamma_b, a_n, a2_hi, a2_lo);

  GemmArgs g2{};  // qkvg = a2 @ W4T + bq4
  g2.Ah = a2_hi; g2.Al = a2_lo; g2.Bh = W4T_hi; g2.Bl = W4T_lo;
  g2.lda = 768; g2.ldb = 768; g2.K = 768; g2.C = qkvg; g2.ldc = 3072; g2.aux0 = bq4;
  k_gemm<4,4,true,1><<<dim3(6,24,1), blk, 0, stream>>>(g2);

  k_qkvg_post<<<dim3(960), blk, 0, stream>>>(qkvg, qp, kp, vt, gate);

  GemmArgs g3{};  // scores[z] = qp_z @ kp_z^T * scale + bias3[z]
  g3.Ah = qp; g3.Bh = kp; g3.lda = 1024; g3.ldb = 1024; g3.K = 64;
  g3.sAz = 64; g3.sBz = 64; g3.C = scores; g3.ldc = 768; g3.sCz = NN_;
  g3.aux0 = bias3; g3.scale = 0.14433756729740643f;
  k_gemm<4,4,false,2><<<dim3(6,6,16), blk, 0, stream>>>(g3);

  k_softmax<<<dim3(3072), blk, 0, stream>>>(scores, attn);

  GemmArgs g4{};  // o[z] = attn_z @ vt_z^T, * gate, split-store
  g4.Ah = attn; g4.Bh = vt; g4.lda = 768; g4.ldb = 768; g4.K = 768;
  g4.sAz = NN_; g4.sBz = 64*768; g4.aux0 = gate; g4.oHi = o_hi; g4.oLo = o_lo;
  k_gemm<4,2,false,3><<<dim3(6,1,16), blk, 0, stream>>>(g4);

  GemmArgs g5{};  // out1 = o @ WpT
  g5.Ah = o_hi; g5.Al = o_lo; g5.Bh = WpT_hi; g5.Bl = WpT_lo;
  g5.lda = 768; g5.ldb = 768; g5.K = 768; g5.C = out1; g5.ldc = 768;
  k_gemm<4,4,true,0><<<dim3(6,6,1), blk, 0, stream>>>(g5);

  GemmArgs g6{};  // out = sigmoid(s @ WoutT + bout) * out1
  g6.Ah = s_hi; g6.Al = s_lo; g6.Bh = WoT_hi; g6.Bl = WoT_lo;
  g6.lda = 384; g6.ldb = 384; g6.K = 384; g6.C = out; g6.ldc = 768;
  g6.aux0 = out1; g6.aux1 = bout;
  k_gemm<4,4,true,4><<<dim3(6,6,1), blk, 0, stream>>>(g6);
}

// Round 4
// 689.601 us; speedup vs baseline: 1.2031x; 1.2031x over previous
//
#include <hip/hip_runtime.h>

#define N_ 768
#define S_ 384
#define H_ 16
#define D_ 48
#define P_ 128
#define NN_ (768*768)

typedef __attribute__((ext_vector_type(8))) short bf16x8;
typedef __attribute__((ext_vector_type(4))) float f32x4;

__device__ __forceinline__ unsigned short f2bf(float x) {
  unsigned int u = __float_as_uint(x);
  u = (u + 0x7fffu + ((u >> 16) & 1u)) >> 16;
  return (unsigned short)u;
}
__device__ __forceinline__ float bf2f(unsigned short h) {
  return __uint_as_float(((unsigned int)h) << 16);
}
__device__ __forceinline__ float sigm(float x) { return 1.f / (1.f + __expf(-x)); }

// split 8 floats into bf16 hi (truncated) and lo (exact residual, RN)
__device__ __forceinline__ void split8(const float4& a, const float4& b,
                                       bf16x8& hi, bf16x8& lo) {
  float xs[8] = {a.x, a.y, a.z, a.w, b.x, b.y, b.z, b.w};
  union { bf16x8 v; unsigned int u[4]; } Hh, Ll;
  #pragma unroll
  for (int i = 0; i < 4; ++i) {
    unsigned int u0 = __float_as_uint(xs[2*i]);
    unsigned int u1 = __float_as_uint(xs[2*i+1]);
    float l0 = xs[2*i]   - __uint_as_float(u0 & 0xFFFF0000u);
    float l1 = xs[2*i+1] - __uint_as_float(u1 & 0xFFFF0000u);
    Hh.u[i] = (u0 >> 16) | (u1 & 0xFFFF0000u);
    Ll.u[i] = (unsigned int)f2bf(l0) | ((unsigned int)f2bf(l1) << 16);
  }
  hi = Hh.v; lo = Ll.v;
}

// ---------------- LN prep: a_n (fp32), s_n (split), s (split), bq4, wT (split W'), c1/c2 ----------------
__global__ __launch_bounds__(256) void k_ln_prep(
    const float* __restrict__ a, const float* __restrict__ s,
    const float* __restrict__ ln_s_w, const float* __restrict__ bq,
    const float* __restrict__ ln_p_w, const float* __restrict__ ln_p_b,
    const float* __restrict__ Wb,
    float* __restrict__ a_n,
    unsigned short* __restrict__ s_n_hi, unsigned short* __restrict__ s_n_lo,
    unsigned short* __restrict__ s_hi, unsigned short* __restrict__ s_lo,
    float* __restrict__ bq4,
    unsigned short* __restrict__ wT_hi, unsigned short* __restrict__ wT_lo,
    float* __restrict__ c12)
{
  int b = blockIdx.x;
  int t = threadIdx.x;
  if (b == N_) {  // aux block
    for (int j = t; j < 3072; j += 256) bq4[j] = (j < 768) ? bq[j] : 0.f;
    // wT[h][p] = ln_p_w[p] * Wb[p][h], truncation-split to bf16 hi/lo
    for (int idx = t; idx < 2048; idx += 256) {
      int p = idx & 127, h = idx >> 7;
      float w = ln_p_w[p] * Wb[p*16 + h];
      unsigned int u = __float_as_uint(w);
      float lo = w - __uint_as_float(u & 0xFFFF0000u);
      wT_hi[h*128 + p] = (unsigned short)(u >> 16);
      wT_lo[h*128 + p] = f2bf(lo);
    }
    if (t < 16) {
      float c1 = 0.f, c2 = 0.f;
      for (int p = 0; p < 128; ++p) { float wb = Wb[p*16 + t]; c1 += ln_p_w[p]*wb; c2 += ln_p_b[p]*wb; }
      c12[t] = c1; c12[16+t] = c2;
    }
    return;
  }
  __shared__ float red[16];
  int w = t >> 6, l = t & 63;
  // ---- a row (768) ----
  float v0 = a[b*N_ + t], v1 = a[b*N_ + 256 + t], v2 = a[b*N_ + 512 + t];
  float sm = v0+v1+v2, sq = v0*v0 + v1*v1 + v2*v2;
  #pragma unroll
  for (int o = 32; o; o >>= 1) { sm += __shfl_xor(sm, o); sq += __shfl_xor(sq, o); }
  if (l == 0) { red[w] = sm; red[8+w] = sq; }
  __syncthreads();
  float Sa = red[0]+red[1]+red[2]+red[3];
  float Qa = red[8]+red[9]+red[10]+red[11];
  float mean = Sa * (1.f/768.f);
  float var  = Qa * (1.f/768.f) - mean*mean;
  float inv  = rsqrtf(var + 1e-5f);
  a_n[b*N_ + t]       = (v0-mean)*inv;
  a_n[b*N_ + 256 + t] = (v1-mean)*inv;
  a_n[b*N_ + 512 + t] = (v2-mean)*inv;
  __syncthreads();
  // ---- s row (384) ----
  float u0 = s[b*S_ + t];
  float u1 = (t < 128) ? s[b*S_ + 256 + t] : 0.f;
  float sm2 = u0+u1, sq2 = u0*u0 + u1*u1;
  #pragma unroll
  for (int o = 32; o; o >>= 1) { sm2 += __shfl_xor(sm2, o); sq2 += __shfl_xor(sq2, o); }
  if (l == 0) { red[w] = sm2; red[8+w] = sq2; }
  __syncthreads();
  float Ss = red[0]+red[1]+red[2]+red[3];
  float Qs = red[8]+red[9]+red[10]+red[11];
  float means = Ss * (1.f/384.f);
  float vars  = Qs * (1.f/384.f) - means*means;
  float invs  = rsqrtf(vars + 1e-5f);
  {
    float sn = (u0 - means)*invs*ln_s_w[t];
    unsigned short h = f2bf(sn); s_n_hi[b*S_+t] = h; s_n_lo[b*S_+t] = f2bf(sn - bf2f(h));
    unsigned short hr = f2bf(u0); s_hi[b*S_+t] = hr; s_lo[b*S_+t] = f2bf(u0 - bf2f(hr));
  }
  if (t < 128) {
    int c = 256 + t;
    float sn = (u1 - means)*invs*ln_s_w[c];
    unsigned short h = f2bf(sn); s_n_hi[b*S_+c] = h; s_n_lo[b*S_+c] = f2bf(sn - bf2f(h));
    unsigned short hr = f2bf(u1); s_hi[b*S_+c] = hr; s_lo[b*S_+c] = f2bf(u1 - bf2f(hr));
  }
}

// ---------------- transpose + split-convert weights ----------------
struct TDesc { const float* src; unsigned short* hi; unsigned short* lo; int R; int C; };
struct TArgs { TDesc d[8]; };
__global__ __launch_bounds__(256) void k_transpose(TArgs args)
{
  TDesc dd = args.d[blockIdx.z];
  int c0 = blockIdx.x * 32, r0 = blockIdx.y * 32;
  if (r0 >= dd.R || c0 >= dd.C) return;
  __shared__ float tile[32][33];
  int tx = threadIdx.x & 31, ty = threadIdx.x >> 5;
  #pragma unroll
  for (int p = 0; p < 4; ++p) {
    int r = ty + p*8;
    tile[r][tx] = dd.src[(r0 + r)*dd.C + c0 + tx];
  }
  __syncthreads();
  #pragma unroll
  for (int p = 0; p < 4; ++p) {
    int r = ty + p*8;
    float x = tile[tx][r];
    unsigned short h = f2bf(x);
    int oidx = (c0 + r)*dd.R + r0 + tx;
    dd.hi[oidx] = h; dd.lo[oidx] = f2bf(x - bf2f(h));
  }
}

// ---------------- pair bias via MFMA (split-bf16) ----------------
// wave handles 16 positions: A-operand = wT (rows=16 heads), B-operand = x rows (cols=16 positions)
// D[h][pos]; stats land at lane&15 = pos, matching B-fragment row index. Epilogue:
// bias = inv*(x.W') - inv*mu*c1[h] + c2[h] + beta[pos]
__global__ __launch_bounds__(256) void k_pair_bias(
    const float* __restrict__ pair, const float* __restrict__ beta,
    const unsigned short* __restrict__ wT_hi, const unsigned short* __restrict__ wT_lo,
    const float* __restrict__ c12, float* __restrict__ bias3)
{
  int t = threadIdx.x, l = t & 63, w = t >> 6;
  int pos0 = blockIdx.x * 64 + w * 16;
  int r = l & 15, kg = (l >> 4) * 8;
  // W' fragments (A operand): row = head = r, k-contiguous
  bf16x8 wh[4], wl[4];
  #pragma unroll
  for (int ks = 0; ks < 4; ++ks) {
    wh[ks] = *(const bf16x8*)(wT_hi + r*128 + ks*32 + kg);
    wl[ks] = *(const bf16x8*)(wT_lo + r*128 + ks*32 + kg);
  }
  // x loads: row = position pos0 + r
  const float* px = pair + (long)(pos0 + r) * 128;
  float4 xa[4], xb[4];
  #pragma unroll
  for (int ks = 0; ks < 4; ++ks) {
    xa[ks] = *(const float4*)(px + ks*32 + kg);
    xb[ks] = *(const float4*)(px + ks*32 + kg + 4);
  }
  float bv = beta[pos0 + r];
  // stats over this row's 32 elems (independent accumulates), then 2 butterflies
  float sm = 0.f, sq = 0.f;
  #pragma unroll
  for (int ks = 0; ks < 4; ++ks) {
    sm += xa[ks].x + xa[ks].y + xa[ks].z + xa[ks].w;
    sm += xb[ks].x + xb[ks].y + xb[ks].z + xb[ks].w;
    sq = fmaf(xa[ks].x, xa[ks].x, sq); sq = fmaf(xa[ks].y, xa[ks].y, sq);
    sq = fmaf(xa[ks].z, xa[ks].z, sq); sq = fmaf(xa[ks].w, xa[ks].w, sq);
    sq = fmaf(xb[ks].x, xb[ks].x, sq); sq = fmaf(xb[ks].y, xb[ks].y, sq);
    sq = fmaf(xb[ks].z, xb[ks].z, sq); sq = fmaf(xb[ks].w, xb[ks].w, sq);
  }
  sm += __shfl_xor(sm, 16); sm += __shfl_xor(sm, 32);
  sq += __shfl_xor(sq, 16); sq += __shfl_xor(sq, 32);
  float mean = sm * (1.f/128.f);
  float var  = sq * (1.f/128.f) - mean*mean;
  float inv  = rsqrtf(var + 1e-5f);
  // split-convert and MFMA (3-term Ootomo)
  f32x4 acc = {};
  #pragma unroll
  for (int ks = 0; ks < 4; ++ks) {
    bf16x8 xh, xl;
    split8(xa[ks], xb[ks], xh, xl);
    acc = __builtin_amdgcn_mfma_f32_16x16x32_bf16(wh[ks], xh, acc, 0, 0, 0);
    acc = __builtin_amdgcn_mfma_f32_16x16x32_bf16(wl[ks], xh, acc, 0, 0, 0);
    acc = __builtin_amdgcn_mfma_f32_16x16x32_bf16(wh[ks], xl, acc, 0, 0, 0);
  }
  // epilogue: lane's col = pos (l&15), rows = h = (l>>4)*4 + ri
  long pos = pos0 + r;
  int hb = (l >> 4) * 4;
  #pragma unroll
  for (int ri = 0; ri < 4; ++ri) {
    int h = hb + ri;
    float outv = inv*acc[ri] - inv*mean*c12[h] + c12[16 + h] + bv;
    bias3[(long)h*NN_ + pos] = outv;
  }
}

// ---------------- generic NT MFMA GEMM (bf16, optional Ootomo split), fused epilogues ----------------
struct GemmArgs {
  const unsigned short* Ah; const unsigned short* Al;
  const unsigned short* Bh; const unsigned short* Bl;
  int lda, ldb, K;
  long sAz, sBz;
  float* C; int ldc; long sCz;
  const float* aux0; const float* aux1;
  unsigned short* oHi; unsigned short* oLo;
  float scale;
};

// EPI: 0=store f32, 1=+biasvec, 2=scores(*scale + bias3[z]), 3=PV(*gate, split-store o), 4=final out
template<int WTM, int WTN, bool SPLIT, int EPI>
__global__ __launch_bounds__(256) void k_gemm(GemmArgs g)
{
  constexpr int BM = 2*WTM*16, BN = 2*WTN*16;
  int z = blockIdx.z;
  int m0 = blockIdx.x * BM, n0 = blockIdx.y * BN;
  int t = threadIdx.x, l = t & 63, w = t >> 6;
  int wm = (w >> 1)*(WTM*16), wn = (w & 1)*(WTN*16);
  int r = l & 15, kg = (l >> 4)*8;
  const unsigned short* Ah = g.Ah + (long)z*g.sAz;
  const unsigned short* Bh = g.Bh + (long)z*g.sBz;
  const unsigned short* Al = nullptr; const unsigned short* Bl = nullptr;
  if constexpr (SPLIT) { Al = g.Al + (long)z*g.sAz; Bl = g.Bl + (long)z*g.sBz; }
  f32x4 acc[WTM][WTN] = {};
  for (int k0 = 0; k0 < g.K; k0 += 32) {
    bf16x8 ah[WTM], bh[WTN], al[WTM], bl[WTN];
    #pragma unroll
    for (int mt = 0; mt < WTM; ++mt) {
      long off = (long)(m0 + wm + mt*16 + r)*g.lda + k0 + kg;
      ah[mt] = *(const bf16x8*)(Ah + off);
      if constexpr (SPLIT) al[mt] = *(const bf16x8*)(Al + off);
    }
    #pragma unroll
    for (int nt = 0; nt < WTN; ++nt) {
      long off = (long)(n0 + wn + nt*16 + r)*g.ldb + k0 + kg;
      bh[nt] = *(const bf16x8*)(Bh + off);
      if constexpr (SPLIT) bl[nt] = *(const bf16x8*)(Bl + off);
    }
    #pragma unroll
    for (int mt = 0; mt < WTM; ++mt) {
      #pragma unroll
      for (int nt = 0; nt < WTN; ++nt) {
        acc[mt][nt] = __builtin_amdgcn_mfma_f32_16x16x32_bf16(ah[mt], bh[nt], acc[mt][nt], 0, 0, 0);
        if constexpr (SPLIT) {
          acc[mt][nt] = __builtin_amdgcn_mfma_f32_16x16x32_bf16(al[mt], bh[nt], acc[mt][nt], 0, 0, 0);
          acc[mt][nt] = __builtin_amdgcn_mfma_f32_16x16x32_bf16(ah[mt], bl[nt], acc[mt][nt], 0, 0, 0);
        }
      }
    }
  }
  int rb = (l >> 4)*4, cl = l & 15;
  #pragma unroll
  for (int mt = 0; mt < WTM; ++mt)
  #pragma unroll
  for (int nt = 0; nt < WTN; ++nt)
  #pragma unroll
  for (int ri = 0; ri < 4; ++ri) {
    int row = m0 + wm + mt*16 + rb + ri;
    int col = n0 + wn + nt*16 + cl;
    float v = acc[mt][nt][ri];
    if constexpr (EPI == 0) {
      g.C[(long)z*g.sCz + (long)row*g.ldc + col] = v;
    } else if constexpr (EPI == 1) {
      g.C[(long)row*g.ldc + col] = v + g.aux0[col];
    } else if constexpr (EPI == 2) {
      g.C[(long)z*g.sCz + (long)row*g.ldc + col] =
          v*g.scale + g.aux0[(long)z*NN_ + (long)row*N_ + col];
    } else if constexpr (EPI == 3) {
      if (col < D_) {
        long oidx = (long)row*N_ + z*D_ + col;
        float val = v * g.aux0[oidx];
        unsigned short hh = f2bf(val);
        g.oHi[oidx] = hh; g.oLo[oidx] = f2bf(val - bf2f(hh));
      }
    } else if constexpr (EPI == 4) {
      float sgv = sigm(v + g.aux1[col]);
      long oidx = (long)row*g.ldc + col;
      g.C[oidx] = sgv * g.aux0[oidx];
    }
  }
}

// ---------------- a2 = sigmoid(gs_gamma + gamma_b) * a_n + gs_shift  (split-store) ----------------
__global__ __launch_bounds__(256) void k_a2(
    const float* __restrict__ gs, const float* __restrict__ gamma_b,
    const float* __restrict__ a_n,
    unsigned short* __restrict__ a2h, unsigned short* __restrict__ a2l)
{
  int i = blockIdx.x;
  int j = blockIdx.y*256 + threadIdx.x;
  float val = sigm(gs[(long)i*1536 + j] + gamma_b[j]) * a_n[(long)i*N_ + j]
            + gs[(long)i*1536 + 768 + j];
  unsigned short h = f2bf(val);
  long idx = (long)i*N_ + j;
  a2h[idx] = h; a2l[idx] = f2bf(val - bf2f(h));
}

// ---------------- qkvg post: qp/kp (bf16, d padded to 64 with zeros), v^T (bf16), gate (fp32) ----------------
__global__ __launch_bounds__(256) void k_qkvg_post(
    const float* __restrict__ qkvg,
    unsigned short* __restrict__ qp, unsigned short* __restrict__ kp,
    unsigned short* __restrict__ vt, float* __restrict__ gg)
{
  int b = blockIdx.x;
  int t = threadIdx.x;
  if (b < N_) {
    long i = b;
    #pragma unroll
    for (int e = 0; e < 4; ++e) {
      int c = t + e*256;            // 0..1023
      int h = c >> 6, d = c & 63;
      float qv = (d < D_) ? qkvg[i*3072 + h*D_ + d] : 0.f;
      float kv = (d < D_) ? qkvg[i*3072 + 768 + h*D_ + d] : 0.f;
      qp[i*1024 + c] = f2bf(qv);
      kp[i*1024 + c] = f2bf(kv);
    }
    #pragma unroll
    for (int e = 0; e < 3; ++e) {
      int c = t + e*256;
      gg[i*N_ + c] = sigm(qkvg[i*3072 + 2304 + c]);
    }
  } else {
    __shared__ float tile[64][49];
    int b2 = b - N_;                // 0..191
    int h = b2 / 12, i0 = (b2 % 12) * 64;
    #pragma unroll
    for (int e = 0; e < 12; ++e) {
      int idx = t + e*256;          // 0..3071
      int il = idx / 48, d = idx % 48;
      tile[il][d] = qkvg[(long)(i0+il)*3072 + 1536 + h*D_ + d];
    }
    __syncthreads();
    #pragma unroll
    for (int e = 0; e < 12; ++e) {
      int idx = t + e*256;
      int d = idx >> 6, il = idx & 63;
      vt[(long)h*49152 + (long)d*N_ + i0 + il] = f2bf(tile[il][d]);
    }
  }
}

// ---------------- softmax over rows of scores -> attn (bf16) ----------------
__global__ __launch_bounds__(256) void k_softmax(
    const float* __restrict__ scores, unsigned short* __restrict__ attn)
{
  int row = blockIdx.x*4 + (threadIdx.x >> 6);
  int l = threadIdx.x & 63;
  const float* src = scores + (long)row*N_;
  float x[12];
  #pragma unroll
  for (int e = 0; e < 12; ++e) x[e] = src[l + e*64];
  float m = x[0];
  #pragma unroll
  for (int e = 1; e < 12; ++e) m = fmaxf(m, x[e]);
  #pragma unroll
  for (int o = 32; o; o >>= 1) m = fmaxf(m, __shfl_xor(m, o));
  float ssum = 0.f;
  #pragma unroll
  for (int e = 0; e < 12; ++e) { x[e] = __expf(x[e] - m); ssum += x[e]; }
  #pragma unroll
  for (int o = 32; o; o >>= 1) ssum += __shfl_xor(ssum, o);
  float invs = 1.f / ssum;
  unsigned short* dst = attn + (long)row*N_;
  #pragma unroll
  for (int e = 0; e < 12; ++e) dst[l + e*64] = f2bf(x[e]*invs);
}

// ---------------- launch ----------------
extern "C" void kernel_launch(void* const* d_in, const int* in_sizes, int n_in,
                              void* d_out, int out_size, void* d_ws, size_t ws_size,
                              hipStream_t stream) {
  const float* a      = (const float*)d_in[0];
  const float* s      = (const float*)d_in[1];
  const float* pair   = (const float*)d_in[2];
  const float* beta   = (const float*)d_in[3];
  const float* ln_s_w = (const float*)d_in[4];
  const float* gamma_w= (const float*)d_in[5];
  const float* gamma_b= (const float*)d_in[6];
  const float* shift_w= (const float*)d_in[7];
  const float* Wq     = (const float*)d_in[8];
  const float* bq     = (const float*)d_in[9];
  const float* Wk     = (const float*)d_in[10];
  const float* Wv     = (const float*)d_in[11];
  const float* ln_p_w = (const float*)d_in[12];
  const float* ln_p_b = (const float*)d_in[13];
  const float* Wb     = (const float*)d_in[14];
  const float* Wg     = (const float*)d_in[15];
  const float* Wp     = (const float*)d_in[16];
  const float* Wout   = (const float*)d_in[17];
  const float* bout   = (const float*)d_in[18];
  float* out = (float*)d_out;
  (void)in_sizes; (void)n_in; (void)out_size; (void)ws_size;

  char* ws = (char*)d_ws;
  size_t off = 0;
  auto alloc = [&](size_t bytes) -> char* {
    char* p = ws + off;
    off = (off + bytes + 255) & ~(size_t)255;
    return p;
  };
  float* bias3   = (float*)alloc((size_t)H_*NN_*4);      // 37.75 MB
  float* scores  = (float*)alloc((size_t)H_*NN_*4);      // 37.75 MB
  unsigned short* W4T_hi  = (unsigned short*)alloc((size_t)3072*768*2);
  unsigned short* W4T_lo  = (unsigned short*)alloc((size_t)3072*768*2);
  unsigned short* gsT_hi  = (unsigned short*)alloc((size_t)1536*384*2);
  unsigned short* gsT_lo  = (unsigned short*)alloc((size_t)1536*384*2);
  unsigned short* WpT_hi  = (unsigned short*)alloc((size_t)768*768*2);
  unsigned short* WpT_lo  = (unsigned short*)alloc((size_t)768*768*2);
  unsigned short* WoT_hi  = (unsigned short*)alloc((size_t)768*384*2);
  unsigned short* WoT_lo  = (unsigned short*)alloc((size_t)768*384*2);
  float* a_n     = (float*)alloc((size_t)N_*N_*4);
  unsigned short* s_n_hi = (unsigned short*)alloc((size_t)N_*S_*2);
  unsigned short* s_n_lo = (unsigned short*)alloc((size_t)N_*S_*2);
  unsigned short* s_hi   = (unsigned short*)alloc((size_t)N_*S_*2);
  unsigned short* s_lo   = (unsigned short*)alloc((size_t)N_*S_*2);
  float* bq4     = (float*)alloc(3072*4);
  unsigned short* wT_hi  = (unsigned short*)alloc(16*128*2);
  unsigned short* wT_lo  = (unsigned short*)alloc(16*128*2);
  float* c12     = (float*)alloc(32*4);
  unsigned short* a2_hi  = (unsigned short*)alloc((size_t)N_*N_*2);
  unsigned short* a2_lo  = (unsigned short*)alloc((size_t)N_*N_*2);
  float* qkvg    = (float*)alloc((size_t)N_*3072*4);     // gs aliases this
  unsigned short* qp = (unsigned short*)alloc((size_t)N_*1024*2);
  unsigned short* kp = (unsigned short*)alloc((size_t)N_*1024*2);
  unsigned short* vt = (unsigned short*)alloc((size_t)H_*64*N_*2);
  float* gate    = (float*)alloc((size_t)N_*N_*4);
  // aliases (dead-buffer reuse)
  float* gs = qkvg;                                   // 768x1536 fp32, dead before GEMM2 writes qkvg
  unsigned short* attn = (unsigned short*)bias3;      // bias3 dead after scores GEMM
  unsigned short* o_hi = (unsigned short*)scores;     // scores dead after softmax
  unsigned short* o_lo = (unsigned short*)((char*)scores + (size_t)N_*N_*2);
  float* out1 = (float*)((char*)scores + (size_t)N_*N_*4);

  dim3 blk(256);

  k_ln_prep<<<dim3(N_ + 1), blk, 0, stream>>>(a, s, ln_s_w, bq, ln_p_w, ln_p_b, Wb,
      a_n, s_n_hi, s_n_lo, s_hi, s_lo, bq4, wT_hi, wT_lo, c12);

  TArgs ta;
  ta.d[0] = {gamma_w, gsT_hi,               gsT_lo,               384, 768};
  ta.d[1] = {shift_w, gsT_hi + 768*384,     gsT_lo + 768*384,     384, 768};
  ta.d[2] = {Wq,      W4T_hi,               W4T_lo,               768, 768};
  ta.d[3] = {Wk,      W4T_hi + 1*768*768,   W4T_lo + 1*768*768,   768, 768};
  ta.d[4] = {Wv,      W4T_hi + 2*768*768,   W4T_lo + 2*768*768,   768, 768};
  ta.d[5] = {Wg,      W4T_hi + 3*768*768,   W4T_lo + 3*768*768,   768, 768};
  ta.d[6] = {Wp,      WpT_hi,               WpT_lo,               768, 768};
  ta.d[7] = {Wout,    WoT_hi,               WoT_lo,               384, 768};
  k_transpose<<<dim3(24, 24, 8), blk, 0, stream>>>(ta);

  k_pair_bias<<<dim3(NN_/64), blk, 0, stream>>>(pair, beta, wT_hi, wT_lo, c12, bias3);

  GemmArgs g1{};  // gs = s_n @ [gammaT|shiftT]
  g1.Ah = s_n_hi; g1.Al = s_n_lo; g1.Bh = gsT_hi; g1.Bl = gsT_lo;
  g1.lda = 384; g1.ldb = 384; g1.K = 384; g1.C = gs; g1.ldc = 1536;
  k_gemm<2,2,true,0><<<dim3(12,24,1), blk, 0, stream>>>(g1);

  k_a2<<<dim3(768,3), blk, 0, stream>>>(gs, gamma_b, a_n, a2_hi, a2_lo);

  GemmArgs g2{};  // qkvg = a2 @ W4T + bq4
  g2.Ah = a2_hi; g2.Al = a2_lo; g2.Bh = W4T_hi; g2.Bl = W4T_lo;
  g2.lda = 768; g2.ldb = 768; g2.K = 768; g2.C = qkvg; g2.ldc = 3072; g2.aux0 = bq4;
  k_gemm<2,2,true,1><<<dim3(12,48,1), blk, 0, stream>>>(g2);

  k_qkvg_post<<<dim3(960), blk, 0, stream>>>(qkvg, qp, kp, vt, gate);

  GemmArgs g3{};  // scores[z] = qp_z @ kp_z^T * scale + bias3[z]
  g3.Ah = qp; g3.Bh = kp; g3.lda = 1024; g3.ldb = 1024; g3.K = 64;
  g3.sAz = 64; g3.sBz = 64; g3.C = scores; g3.ldc = 768; g3.sCz = NN_;
  g3.aux0 = bias3; g3.scale = 0.14433756729740643f;
  k_gemm<4,4,false,2><<<dim3(6,6,16), blk, 0, stream>>>(g3);

  k_softmax<<<dim3(3072), blk, 0, stream>>>(scores, attn);

  GemmArgs g4{};  // o[z] = attn_z @ vt_z^T, * gate, split-store
  g4.Ah = attn; g4.Bh = vt; g4.lda = 768; g4.ldb = 768; g4.K = 768;
  g4.sAz = NN_; g4.sBz = 64*768; g4.aux0 = gate; g4.oHi = o_hi; g4.oLo = o_lo;
  k_gemm<1,2,false,3><<<dim3(24,1,16), blk, 0, stream>>>(g4);

  GemmArgs g5{};  // out1 = o @ WpT
  g5.Ah = o_hi; g5.Al = o_lo; g5.Bh = WpT_hi; g5.Bl = WpT_lo;
  g5.lda = 768; g5.ldb = 768; g5.K = 768; g5.C = out1; g5.ldc = 768;
  k_gemm<2,2,true,0><<<dim3(12,12,1), blk, 0, stream>>>(g5);

  GemmArgs g6{};  // out = sigmoid(s @ WoutT + bout) * out1
  g6.Ah = s_hi; g6.Al = s_lo; g6.Bh = WoT_hi; g6.Bl = WoT_lo;
  g6.lda = 384; g6.ldb = 384; g6.K = 384; g6.C = out; g6.ldc = 768;
  g6.aux0 = out1; g6.aux1 = bout;
  k_gemm<2,2,true,4><<<dim3(12,12,1), blk, 0, stream>>>(g6);
}